// Round 1
// 1038.707 us; speedup vs baseline: 1.1436x; 1.1436x over previous
//
#include <hip/hip_runtime.h>
#include <cstddef>

// Sinkhorn matcher: B=32, N=4096, C=558 (+1 dustbin col = M=559), 5 iters, T=1.
// Linear-domain: K = exp(aug); u = mu/(K v); v = nu/(K^T u).
//
// Key structural fact: ~50% of rows have visible_mask=0 -> u=0 exactly ->
// zero contribution to column sums and all-zero output rows (hard=0).
// k_init compacts a per-batch visible-row index list (invisible list packed
// from the back of the same array). Iteration + final passes touch ONLY
// visible rows (~146 MB/pass, fits 256 MB Infinity Cache for cross-iteration
// reuse); invisible rows are zero-filled with store-only code in k_final.

namespace {
constexpr int B_ = 32, N_ = 4096, C_ = 558, M_ = 559, MP_ = 560;

// workspace layout (in 4-byte words)
constexpr size_t U_OFF = 0;                              // u: B*N floats
constexpr size_t V_OFF = (size_t)B_ * N_;                // v: B*MP floats
constexpr size_t A_OFF = V_OFF + (size_t)B_ * MP_;       // acc: B*MP floats
constexpr size_t I_OFF = A_OFF + (size_t)B_ * MP_;       // invnv: B floats
constexpr size_t NV_OFF = I_OFF + B_;                    // nv: B ints
constexpr size_t VIS_OFF = NV_OFF + B_;                  // index list: B*N ints
                                                         // [0,nv) visible, [nv,N) invisible

// output layout (floats), concatenated in reference return order
constexpr size_t FULL_OFF = 0;                                   // B*N*559
constexpr size_t SOFT_OFF = (size_t)B_ * N_ * M_;                // B*N*558
constexpr size_t HARD_OFF = SOFT_OFF + (size_t)B_ * N_ * C_;     // B*N
constexpr size_t DUST_OFF = HARD_OFF + (size_t)B_ * N_;          // B*N

typedef float f2_t __attribute__((ext_vector_type(2)));

__device__ __forceinline__ void st_nt(float* p, float v) {
    __builtin_nontemporal_store(v, p);
}
__device__ __forceinline__ void st_nt2(float* p, float a, float b) {
    f2_t v; v.x = a; v.y = b;
    __builtin_nontemporal_store(v, (f2_t*)p);
}
} // namespace

// Per-batch: count visible, build compacted index list (visible from front,
// invisible from back), init v=1, zero acc.
__global__ void k_init(const int* __restrict__ vm, float* __restrict__ ws) {
    const int b = blockIdx.x;
    const int t = threadIdx.x;  // 256 threads
    const int* __restrict__ row = vm + (size_t)b * N_;
    int* __restrict__ visl = ((int*)ws) + VIS_OFF + (size_t)b * N_;

    // each thread owns rows n = j*256 + t (coalesced reads)
    int m[16];
    int cnt = 0;
#pragma unroll
    for (int j = 0; j < 16; ++j) { m[j] = (row[j * 256 + t] != 0); cnt += m[j]; }

    __shared__ int scn[256];
    scn[t] = cnt;
    __syncthreads();
    for (int off = 1; off < 256; off <<= 1) {
        const int add = (t >= off) ? scn[t - off] : 0;
        __syncthreads();
        scn[t] += add;
        __syncthreads();
    }
    const int inc = scn[t];      // inclusive visible prefix over threads
    const int nv = scn[255];
    int vp = inc - cnt;                    // exclusive visible prefix
    int ip = N_ - 1 - (16 * t - vp);       // back-slot for this thread's invisibles
#pragma unroll
    for (int j = 0; j < 16; ++j) {
        const int n = j * 256 + t;
        if (m[j]) visl[vp++] = n;
        else      visl[ip--] = n;
    }

    if (t == 0) {
        ws[I_OFF + b] = 1.0f / (float)nv;
        ((int*)ws)[NV_OFF + b] = nv;
    }
    for (int c = t; c < MP_; c += 256) {
        ws[V_OFF + (size_t)b * MP_ + c] = 1.0f;
        ws[A_OFF + (size_t)b * MP_ + c] = 0.0f;
    }
}

// One Sinkhorn iteration over VISIBLE rows only.
// Grid: (32, B), block 256 = 4 waves; wave strides the compact list by 128.
// Software pipeline: next index + next row prefetched before current row's
// exp/reduce chain.
__global__ __launch_bounds__(256) void k_row(const float* __restrict__ sc,
                                             const float* __restrict__ dustp,
                                             float* __restrict__ ws) {
    const int b = blockIdx.y;
    const int wid = blockIdx.x * 4 + (threadIdx.x >> 6);
    const int lane = threadIdx.x & 63;

    const float dustE = expf(dustp[0]);  // T = 1
    const float invnv = ws[I_OFF + b];
    const int nv = ((const int*)ws)[NV_OFF + b];
    const int* __restrict__ visl = ((const int*)ws) + VIS_OFF + (size_t)b * N_;
    const float* __restrict__ vrow = ws + V_OFF + (size_t)b * MP_;
    float* __restrict__ acc = ws + A_OFF + (size_t)b * MP_;

    // v fragment: c = k*128 + 2*lane (k<4), tail c = 512+lane
    float2 v2[4];
#pragma unroll
    for (int k = 0; k < 4; ++k) v2[k] = *(const float2*)(vrow + k * 128 + 2 * lane);
    float vt = 0.0f;
    if (lane < 46) vt = vrow[512 + lane];
    else if (lane == 46) vt = vrow[558];

    float2 a2[4] = {{0.f, 0.f}, {0.f, 0.f}, {0.f, 0.f}, {0.f, 0.f}};
    float at = 0.0f;

    int i = wid;
    int n_cur = (i < nv) ? visl[i] : -1;
    float2 x[4];
    float xt = 0.0f;
    if (n_cur >= 0) {
        const float* __restrict__ srow = sc + (size_t)(b * N_ + n_cur) * C_;
#pragma unroll
        for (int k = 0; k < 4; ++k) x[k] = *(const float2*)(srow + k * 128 + 2 * lane);
        if (lane < 46) xt = srow[512 + lane];
    }

    while (n_cur >= 0) {
        // prefetch next row while computing on current
        const int n_nxt = (i + 128 < nv) ? visl[i + 128] : -1;
        float2 y[4];
        float yt = 0.0f;
        if (n_nxt >= 0) {
            const float* __restrict__ srow = sc + (size_t)(b * N_ + n_nxt) * C_;
#pragma unroll
            for (int k = 0; k < 4; ++k) y[k] = *(const float2*)(srow + k * 128 + 2 * lane);
            if (lane < 46) yt = srow[512 + lane];
        }

        float2 e2[4];
#pragma unroll
        for (int k = 0; k < 4; ++k) { e2[k].x = expf(x[k].x); e2[k].y = expf(x[k].y); }
        float et = 0.0f;
        if (lane < 46) et = expf(xt);
        else if (lane == 46) et = dustE;

        float s = et * vt;
#pragma unroll
        for (int k = 0; k < 4; ++k) s += e2[k].x * v2[k].x + e2[k].y * v2[k].y;
#pragma unroll
        for (int m = 1; m < 64; m <<= 1) s += __shfl_xor(s, m, 64);

        const float u = invnv / s;   // row is visible by construction
        if (lane == 0) ws[U_OFF + (size_t)b * N_ + n_cur] = u;

#pragma unroll
        for (int k = 0; k < 4; ++k) { a2[k].x += e2[k].x * u; a2[k].y += e2[k].y * u; }
        at += et * u;

        i += 128;
        n_cur = n_nxt;
#pragma unroll
        for (int k = 0; k < 4; ++k) x[k] = y[k];
        xt = yt;
    }

    // flush column partials
#pragma unroll
    for (int k = 0; k < 4; ++k) {
        atomicAdd(&acc[k * 128 + 2 * lane], a2[k].x);
        atomicAdd(&acc[k * 128 + 2 * lane + 1], a2[k].y);
    }
    if (lane <= 46) atomicAdd(&acc[512 + lane], at);  // lane 46 -> c=558
}

// v = nu / colsum; re-zero acc for next iteration.
__global__ void k_vupd(float* __restrict__ ws) {
    const int b = blockIdx.x;
    const float nu = 1.0f / 559.0f;
    for (int c = threadIdx.x; c < M_; c += 256) {
        const float a = ws[A_OFF + (size_t)b * MP_ + c];
        ws[V_OFF + (size_t)b * MP_ + c] = nu / a;
        ws[A_OFF + (size_t)b * MP_ + c] = 0.0f;
    }
}

// Final: visible rows -> P = exp(aug)*u*v (full/soft/hard/dust);
// invisible rows -> store-only zeros (hard = argmax(zeros) = 0).
__global__ __launch_bounds__(256) void k_final(const float* __restrict__ sc,
                                               const float* __restrict__ dustp,
                                               const float* __restrict__ ws,
                                               float* __restrict__ out) {
    const int b = blockIdx.y;
    const int wid = blockIdx.x * 4 + (threadIdx.x >> 6);
    const int lane = threadIdx.x & 63;

    const float dustE = expf(dustp[0]);
    const int nv = ((const int*)ws)[NV_OFF + b];
    const int* __restrict__ visl = ((const int*)ws) + VIS_OFF + (size_t)b * N_;
    const float* __restrict__ vrow = ws + V_OFF + (size_t)b * MP_;

    float2 v2[4];
#pragma unroll
    for (int k = 0; k < 4; ++k) v2[k] = *(const float2*)(vrow + k * 128 + 2 * lane);
    float vt = 0.0f;
    if (lane < 46) vt = vrow[512 + lane];
    else if (lane == 46) vt = vrow[558];

    int i = wid;
    int n_cur = (i < nv) ? visl[i] : -1;
    float2 x[4];
    float xt = 0.0f, ucur = 0.0f;
    if (n_cur >= 0) {
        const float* __restrict__ srow = sc + (size_t)(b * N_ + n_cur) * C_;
#pragma unroll
        for (int k = 0; k < 4; ++k) x[k] = *(const float2*)(srow + k * 128 + 2 * lane);
        if (lane < 46) xt = srow[512 + lane];
        ucur = ws[U_OFF + (size_t)b * N_ + n_cur];
    }

    while (n_cur >= 0) {
        const int n_nxt = (i + 128 < nv) ? visl[i + 128] : -1;
        float2 y[4];
        float yt = 0.0f, unxt = 0.0f;
        if (n_nxt >= 0) {
            const float* __restrict__ srow = sc + (size_t)(b * N_ + n_nxt) * C_;
#pragma unroll
            for (int k = 0; k < 4; ++k) y[k] = *(const float2*)(srow + k * 128 + 2 * lane);
            if (lane < 46) yt = srow[512 + lane];
            unxt = ws[U_OFF + (size_t)b * N_ + n_nxt];
        }

        float2 e2[4];
#pragma unroll
        for (int k = 0; k < 4; ++k) { e2[k].x = expf(x[k].x); e2[k].y = expf(x[k].y); }
        float et = 0.0f;
        if (lane < 46) et = expf(xt);
        else if (lane == 46) et = dustE;

        float2 p2[4];
#pragma unroll
        for (int k = 0; k < 4; ++k) {
            p2[k].x = e2[k].x * ucur * v2[k].x;
            p2[k].y = e2[k].y * ucur * v2[k].y;
        }
        const float pt = et * ucur * vt;  // soft tail value, or dustbin for lane 46

        // full (row stride 559, odd -> scalar dword NT stores, coalesced)
        float* __restrict__ fr = out + FULL_OFF + (size_t)(b * N_ + n_cur) * M_;
#pragma unroll
        for (int k = 0; k < 4; ++k) {
            st_nt(fr + k * 128 + 2 * lane, p2[k].x);
            st_nt(fr + k * 128 + 2 * lane + 1, p2[k].y);
        }
        if (lane <= 46) st_nt(fr + 512 + lane, pt);  // lane 46 -> c=558 (dustbin)

        // soft (row stride 558 -> 8B-aligned float2 NT stores)
        float* __restrict__ so = out + SOFT_OFF + (size_t)(b * N_ + n_cur) * C_;
#pragma unroll
        for (int k = 0; k < 4; ++k) st_nt2(so + k * 128 + 2 * lane, p2[k].x, p2[k].y);
        if (lane < 46) st_nt(so + 512 + lane, pt);

        if (lane == 46) st_nt(out + DUST_OFF + (size_t)b * N_ + n_cur, pt);

        // argmax over c < 558, ties -> lowest index (np semantics)
        float best = -1.0f;
        int bidx = 0x7fffffff;
#pragma unroll
        for (int k = 0; k < 4; ++k) {
            const int c = k * 128 + 2 * lane;
            if (p2[k].x > best) { best = p2[k].x; bidx = c; }
            if (p2[k].y > best) { best = p2[k].y; bidx = c + 1; }
        }
        if (lane < 46 && pt > best) { best = pt; bidx = 512 + lane; }
#pragma unroll
        for (int m = 1; m < 64; m <<= 1) {
            const float ov = __shfl_xor(best, m, 64);
            const int oi = __shfl_xor(bidx, m, 64);
            if (ov > best || (ov == best && oi < bidx)) { best = ov; bidx = oi; }
        }
        if (lane == 0) st_nt(out + HARD_OFF + (size_t)b * N_ + n_cur, (float)bidx);

        i += 128;
        n_cur = n_nxt;
#pragma unroll
        for (int k = 0; k < 4; ++k) x[k] = y[k];
        xt = yt;
        ucur = unxt;
    }

    // invisible rows: exact zeros, store-only
    for (int j = nv + wid; j < N_; j += 128) {
        const int n = visl[j];
        float* __restrict__ fr = out + FULL_OFF + (size_t)(b * N_ + n) * M_;
#pragma unroll
        for (int k = 0; k < 4; ++k) {
            st_nt(fr + k * 128 + 2 * lane, 0.0f);
            st_nt(fr + k * 128 + 2 * lane + 1, 0.0f);
        }
        if (lane <= 46) st_nt(fr + 512 + lane, 0.0f);

        float* __restrict__ so = out + SOFT_OFF + (size_t)(b * N_ + n) * C_;
#pragma unroll
        for (int k = 0; k < 4; ++k) st_nt2(so + k * 128 + 2 * lane, 0.0f, 0.0f);
        if (lane < 46) st_nt(so + 512 + lane, 0.0f);

        if (lane == 0) st_nt(out + HARD_OFF + (size_t)b * N_ + n, 0.0f);
        if (lane == 46) st_nt(out + DUST_OFF + (size_t)b * N_ + n, 0.0f);
    }
}

extern "C" void kernel_launch(void* const* d_in, const int* in_sizes, int n_in,
                              void* d_out, int out_size, void* d_ws, size_t ws_size,
                              hipStream_t stream) {
    const float* sc = (const float*)d_in[0];
    const int* vm = (const int*)d_in[1];
    const float* dustp = (const float*)d_in[2];
    float* out = (float*)d_out;
    float* ws = (float*)d_ws;

    k_init<<<B_, 256, 0, stream>>>(vm, ws);
    for (int it = 0; it < 5; ++it) {
        k_row<<<dim3(32, B_), 256, 0, stream>>>(sc, dustp, ws);
        k_vupd<<<B_, 256, 0, stream>>>(ws);
    }
    k_final<<<dim3(32, B_), 256, 0, stream>>>(sc, dustp, ws, out);
}